// Round 3
// baseline (817.363 us; speedup 1.0000x reference)
//
#include <hip/hip_runtime.h>
#include <math.h>

#define DD 128          // node embedding dim
#define RR 1024         // root nodes
#define TT 4            // trunk types; encoder TT is the output autoencoder
#define LL 64           // levels
#define MM 2048         // nodes per level
#define NBK 16          // nodes per chunk (one MFMA M-tile)
#define PAD16 (MM + 5*NBK)   // 2128 padded slots per level
#define CH (PAD16/NBK)       // 133 chunks per level == grid size of persistent kernel
#define NGRP 17              // barrier groups of 8 WGs (last has 5)
#define GSTRIDE 32           // ints between group counters (cacheline separation)

typedef __attribute__((ext_vector_type(8))) short short8v;   // 8 bf16 (4 VGPRs)
typedef __attribute__((ext_vector_type(4))) float f32x4;

static __device__ __forceinline__ unsigned short f2bf(float f) {
    unsigned u = __float_as_uint(f);
    unsigned r = (u + 0x7fffu + ((u >> 16) & 1u)) >> 16;   // RNE
    return (unsigned short)r;
}

// ---------------------------------------------------------------------------
// Group nodes of each level by encoder type (0..4), chunks of 16, pad 0xFFFF.
// Within-group order is race-dependent but per-node results are independent,
// so d_out is deterministic.
// ---------------------------------------------------------------------------
__global__ void build_order16(const int* __restrict__ types,
                              unsigned short* __restrict__ order) {
    int l = blockIdx.x, tid = threadIdx.x;
    __shared__ int cnt[5], cur[5];
    if (tid < 5) cnt[tid] = 0;
    __syncthreads();
    for (int s = tid; s < PAD16; s += 256) order[l*PAD16 + s] = 0xFFFFu;
    for (int m = tid; m < MM; m += 256) {
        int t = types[l*MM + m];
        int e = (t >= TT) ? TT : t;
        atomicAdd(&cnt[e], 1);
    }
    __syncthreads();
    if (tid == 0) {
        int off = 0;
        for (int e = 0; e < 5; e++) { cur[e] = off; off += ((cnt[e] + NBK - 1)/NBK)*NBK; }
    }
    __syncthreads();
    for (int m = tid; m < MM; m += 256) {
        int t = types[l*MM + m];
        int e = (t >= TT) ? TT : t;
        int pos = atomicAdd(&cur[e], 1);
        order[l*PAD16 + pos] = (unsigned short)m;
    }
}

// ---------------------------------------------------------------------------
// Pre-convert weights to bf16 in MFMA B-fragment order:
//   W1F[e][nt(16)][kk(8)][lane(64)][j(8)]  n = nt*16+(lane&15), k = kk*32+(lane>>4)*8+j
//   W2F[e][nt(8)][kk(8)][lane(64)][j(8)]
// ---------------------------------------------------------------------------
__global__ void convert_weights(const float* __restrict__ W1,
                                const float* __restrict__ W2,
                                unsigned short* __restrict__ W1F,
                                unsigned short* __restrict__ W2F) {
    int tid = blockIdx.x*256 + threadIdx.x;
    if (tid < 5*16*8*64) {
        int lane = tid & 63;
        int kk = (tid >> 6) & 7;
        int nt = (tid >> 9) & 15;
        int e  = tid >> 13;
        int n  = nt*16 + (lane & 15);
        int k0 = kk*32 + (lane >> 4)*8;
        unsigned short v[8];
        #pragma unroll
        for (int j = 0; j < 8; j++) v[j] = f2bf(W1[(e*256 + k0 + j)*256 + n]);
        *(short8v*)&W1F[tid*8] = *(short8v*)v;
    } else if (tid < 5*16*8*64 + 5*8*8*64) {
        int t = tid - 5*16*8*64;
        int lane = t & 63;
        int kk = (t >> 6) & 7;
        int nt = (t >> 9) & 7;
        int e  = t >> 12;
        int n  = nt*16 + (lane & 15);
        int k0 = kk*32 + (lane >> 4)*8;
        unsigned short v[8];
        #pragma unroll
        for (int j = 0; j < 8; j++) v[j] = f2bf(W2[(e*256 + k0 + j)*128 + n]);
        *(short8v*)&W2F[t*8] = *(short8v*)v;
    }
}

// ---------------------------------------------------------------------------
// Persistent cooperative kernel: 133 WGs x 256 threads. WG g owns chunk g of
// every level. Two-stage monotonic device-scope barrier between levels.
// All indirection (order -> par/types) resolved once into LDS descriptors.
// ---------------------------------------------------------------------------
__global__ __launch_bounds__(256, 1) void persist_mfma(
    const unsigned short* __restrict__ W1F, const unsigned short* __restrict__ W2F,
    const float* __restrict__ b1, const float* __restrict__ b2,
    const float* __restrict__ slots, const int* __restrict__ par,
    const int* __restrict__ types, const unsigned short* __restrict__ order,
    float* __restrict__ buf, int* __restrict__ barmem)
{
    __shared__ int4 descs[LL][NBK];            // 16 KB: {node, p0, p1(~slot if out), etype}
    __shared__ int ech[LL];                    // per-level chunk encoder type (-1 = all pad)
    __shared__ unsigned short axF[8*64*8];     // A-frags of x, 8 KB
    __shared__ unsigned short hxF[8*64*8];     // A-frags of h, 8 KB

    int tid = threadIdx.x;
    int wg  = blockIdx.x;

    // ---- prologue: resolve all 64 levels' descriptors for this WG ----
    for (int i = tid; i < LL*NBK; i += 256) {
        int l = i >> 4, s = i & 15;
        unsigned short o = order[l*PAD16 + wg*NBK + s];
        int4 d;
        if (o == 0xFFFFu) {
            d = make_int4(-1, 0, 0, -1);
        } else {
            int gi = l*MM + (int)o;
            int t = types[gi];
            int e = (t >= TT) ? TT : t;
            int p0 = par[2*gi];
            int p1 = (t >= TT) ? ~(t - TT) : par[2*gi + 1];
            d = make_int4((int)o, p0, p1, e);
        }
        descs[l][s] = d;
    }
    __syncthreads();
    for (int i = tid; i < LL; i += 256) ech[i] = descs[i][0].w;
    __syncthreads();

    int w  = tid >> 6;    // wave 0..3
    int lq = tid & 63;    // lane
    int g   = wg >> 3;                 // barrier group
    int gsz = (g == NGRP-1) ? (CH - 8*(NGRP-1)) : 8;
    int* grpc = barmem + g*GSTRIDE;
    int* barc = barmem + NGRP*GSTRIDE;

    for (int l = 0; l < LL; l++) {
        // ---- level barrier (skip for l=0: prep kernels ordered by stream) ----
        if (l > 0) {
            __syncthreads();
            if (tid == 0) {
                __threadfence();   // release: write back this XCD's dirty L2
                int old = __hip_atomic_fetch_add(grpc, 1, __ATOMIC_RELAXED, __HIP_MEMORY_SCOPE_AGENT);
                if (old == l*gsz - 1)
                    __hip_atomic_fetch_add(barc, 1, __ATOMIC_RELAXED, __HIP_MEMORY_SCOPE_AGENT);
                while (__hip_atomic_load(barc, __ATOMIC_RELAXED, __HIP_MEMORY_SCOPE_AGENT) < l*NGRP)
                    __builtin_amdgcn_s_sleep(2);
                __threadfence();   // acquire: invalidate stale caches
            }
            __syncthreads();
        }

        int e = ech[l];
        if (e < 0) continue;   // fully-padded chunk: nothing to compute this level

        // ---- gather x = [buf[p0] | is_out ? slot : buf[p1]] into A-frag LDS ----
        {
            int m = tid >> 4, seg = tid & 15;      // node m, 16-float segment
            int4 d = descs[l][m];
            float vals[16];
            if (d.x >= 0) {
                const float* src;
                if (seg < 8) {
                    src = buf + (size_t)d.y*DD + seg*16;
                } else if (d.z < 0) {
                    src = slots + (size_t)(~d.z)*DD + (seg - 8)*16;
                } else {
                    src = buf + (size_t)d.z*DD + (seg - 8)*16;
                }
                const float4* s4 = (const float4*)src;
                #pragma unroll
                for (int q = 0; q < 4; q++) {
                    float4 v = s4[q];
                    vals[q*4+0] = v.x; vals[q*4+1] = v.y; vals[q*4+2] = v.z; vals[q*4+3] = v.w;
                }
            } else {
                #pragma unroll
                for (int q = 0; q < 16; q++) vals[q] = 0.f;
            }
            #pragma unroll
            for (int h = 0; h < 2; h++) {
                int k = seg*16 + h*8;
                int kk = k >> 5;
                int lane = m + 16*((k >> 3) & 3);
                unsigned short tmp[8];
                #pragma unroll
                for (int j = 0; j < 8; j++) tmp[j] = f2bf(vals[h*8 + j]);
                *(short8v*)&axF[(kk*64 + lane)*8] = *(short8v*)tmp;
            }
        }
        __syncthreads();

        // ---- layer 1: H = GELU(X @ W1[e] + b1[e]) ----
        f32x4 acc[4];
        #pragma unroll
        for (int c = 0; c < 4; c++) {
            float bv = b1[e*256 + w*64 + c*16 + (lq & 15)];
            acc[c] = (f32x4){bv, bv, bv, bv};
        }
        {
            const short8v* Ab = (const short8v*)axF;
            #pragma unroll
            for (int kk = 0; kk < 8; kk++) {
                short8v a = Ab[kk*64 + lq];
                #pragma unroll
                for (int c = 0; c < 4; c++) {
                    int nt = w*4 + c;
                    short8v bfr = *(const short8v*)&W1F[(((e*16 + nt)*8 + kk)*64 + lq)*8];
                    acc[c] = __builtin_amdgcn_mfma_f32_16x16x32_bf16(a, bfr, acc[c], 0, 0, 0);
                }
            }
        }
        #pragma unroll
        for (int c = 0; c < 4; c++) {
            int nh = w*64 + c*16 + (lq & 15);    // hidden index = layer2's k
            int kk2 = nh >> 5;
            int jj  = nh & 7;
            int lhi = 16*((nh >> 3) & 3);
            #pragma unroll
            for (int r = 0; r < 4; r++) {
                int m = (lq >> 4)*4 + r;
                float h = acc[c][r];
                float gg = 0.5f*h*(1.0f + erff(h*0.70710678118654752f));
                hxF[(kk2*64 + (m + lhi))*8 + jj] = f2bf(gg);
            }
        }
        __syncthreads();

        // ---- layer 2: OUT = H @ W2[e] + b2[e] ----
        f32x4 acc2[2];
        #pragma unroll
        for (int c = 0; c < 2; c++) {
            float bv = b2[e*128 + w*32 + c*16 + (lq & 15)];
            acc2[c] = (f32x4){bv, bv, bv, bv};
        }
        {
            const short8v* Hb = (const short8v*)hxF;
            #pragma unroll
            for (int kk = 0; kk < 8; kk++) {
                short8v a = Hb[kk*64 + lq];
                #pragma unroll
                for (int c = 0; c < 2; c++) {
                    int nt = w*2 + c;
                    short8v bfr = *(const short8v*)&W2F[(((e*8 + nt)*8 + kk)*64 + lq)*8];
                    acc2[c] = __builtin_amdgcn_mfma_f32_16x16x32_bf16(a, bfr, acc2[c], 0, 0, 0);
                }
            }
        }
        int baserow = RR + l*MM;
        #pragma unroll
        for (int r = 0; r < 4; r++) {
            int m = (lq >> 4)*4 + r;
            int node = descs[l][m].x;
            if (node >= 0) {
                #pragma unroll
                for (int c = 0; c < 2; c++) {
                    int n = w*32 + c*16 + (lq & 15);
                    buf[(size_t)(baserow + node)*DD + n] = acc2[c][r];
                }
            }
        }
        // loop continues: barrier at top of next iteration orders these stores
    }
}

extern "C" void kernel_launch(void* const* d_in, const int* in_sizes, int n_in,
                              void* d_out, int out_size, void* d_ws, size_t ws_size,
                              hipStream_t stream) {
    const float* root  = (const float*)d_in[0];   // (1024, 128)
    const float* W1    = (const float*)d_in[1];   // (5, 256, 256)
    const float* b1    = (const float*)d_in[2];   // (5, 256)
    const float* W2    = (const float*)d_in[3];   // (5, 256, 128)
    const float* b2    = (const float*)d_in[4];   // (5, 128)
    const float* slots = (const float*)d_in[5];   // (256, 128)
    const int*   par   = (const int*)d_in[6];     // (131072, 2)
    const int*   typ   = (const int*)d_in[7];     // (131072,)
    float* out = (float*)d_out;                   // (132096, 128)

    unsigned short* W1F   = (unsigned short*)d_ws;            // 327680 shorts
    unsigned short* W2F   = W1F + 5*16*8*64*8;                // 163840 shorts
    unsigned short* order = W2F + 5*8*8*64*8;                 // 64*2128 shorts
    int* barmem = (int*)(order + LL*PAD16);                   // (17*32+32) ints

    // roots -> buf[0:R]
    hipMemcpyAsync(out, root, (size_t)RR * DD * sizeof(float),
                   hipMemcpyDeviceToDevice, stream);

    // per-call prep
    build_order16<<<LL, 256, 0, stream>>>(typ, order);
    convert_weights<<<(5*16*8*64 + 5*8*8*64 + 255)/256, 256, 0, stream>>>(W1, W2, W1F, W2F);
    hipMemsetAsync(barmem, 0, (NGRP*GSTRIDE + GSTRIDE)*sizeof(int), stream);

    // persistent cooperative sweep over all 64 levels
    void* args[] = { (void*)&W1F, (void*)&W2F, (void*)&b1, (void*)&b2,
                     (void*)&slots, (void*)&par, (void*)&typ, (void*)&order,
                     (void*)&out, (void*)&barmem };
    hipLaunchCooperativeKernel((const void*)persist_mfma, dim3(CH), dim3(256),
                               args, 0, stream);
}

// Round 4
// 488.216 us; speedup vs baseline: 1.6742x; 1.6742x over previous
//
#include <hip/hip_runtime.h>
#include <math.h>

#define DD 128          // node embedding dim
#define RR 1024         // root nodes
#define TT 4            // trunk types; encoder TT is the output autoencoder
#define LL 64           // levels
#define MM 2048         // nodes per level
#define NBK 16          // nodes per chunk (one MFMA M-tile)
#define PAD16 (MM + 5*NBK)   // 2128 padded slots per level
#define CH (PAD16/NBK)       // 133 chunks per level == grid size of persistent kernel

typedef __attribute__((ext_vector_type(8))) short short8v;   // 8 bf16 (4 VGPRs)
typedef __attribute__((ext_vector_type(4))) float f32x4;

static __device__ __forceinline__ unsigned short f2bf(float f) {
    unsigned u = __float_as_uint(f);
    unsigned r = (u + 0x7fffu + ((u >> 16) & 1u)) >> 16;   // RNE
    return (unsigned short)r;
}

// ---------------------------------------------------------------------------
// Group nodes of each level by encoder type (0..4), chunks of 16, pad 0xFFFF.
// ---------------------------------------------------------------------------
__global__ void build_order16(const int* __restrict__ types,
                              unsigned short* __restrict__ order) {
    int l = blockIdx.x, tid = threadIdx.x;
    __shared__ int cnt[5], cur[5];
    if (tid < 5) cnt[tid] = 0;
    __syncthreads();
    for (int s = tid; s < PAD16; s += 256) order[l*PAD16 + s] = 0xFFFFu;
    for (int m = tid; m < MM; m += 256) {
        int t = types[l*MM + m];
        int e = (t >= TT) ? TT : t;
        atomicAdd(&cnt[e], 1);
    }
    __syncthreads();
    if (tid == 0) {
        int off = 0;
        for (int e = 0; e < 5; e++) { cur[e] = off; off += ((cnt[e] + NBK - 1)/NBK)*NBK; }
    }
    __syncthreads();
    for (int m = tid; m < MM; m += 256) {
        int t = types[l*MM + m];
        int e = (t >= TT) ? TT : t;
        int pos = atomicAdd(&cur[e], 1);
        order[l*PAD16 + pos] = (unsigned short)m;
    }
}

// ---------------------------------------------------------------------------
// Pre-convert weights to bf16 in MFMA B-fragment order:
//   W1F[e][nt(16)][kk(8)][lane(64)][j(8)]  n = nt*16+(lane&15), k = kk*32+(lane>>4)*8+j
//   W2F[e][nt(8)][kk(8)][lane(64)][j(8)]
// ---------------------------------------------------------------------------
__global__ void convert_weights(const float* __restrict__ W1,
                                const float* __restrict__ W2,
                                unsigned short* __restrict__ W1F,
                                unsigned short* __restrict__ W2F) {
    int tid = blockIdx.x*256 + threadIdx.x;
    if (tid < 5*16*8*64) {
        int lane = tid & 63;
        int kk = (tid >> 6) & 7;
        int nt = (tid >> 9) & 15;
        int e  = tid >> 13;
        int n  = nt*16 + (lane & 15);
        int k0 = kk*32 + (lane >> 4)*8;
        unsigned short v[8];
        #pragma unroll
        for (int j = 0; j < 8; j++) v[j] = f2bf(W1[(e*256 + k0 + j)*256 + n]);
        *(short8v*)&W1F[tid*8] = *(short8v*)v;
    } else if (tid < 5*16*8*64 + 5*8*8*64) {
        int t = tid - 5*16*8*64;
        int lane = t & 63;
        int kk = (t >> 6) & 7;
        int nt = (t >> 9) & 7;
        int e  = t >> 12;
        int n  = nt*16 + (lane & 15);
        int k0 = kk*32 + (lane >> 4)*8;
        unsigned short v[8];
        #pragma unroll
        for (int j = 0; j < 8; j++) v[j] = f2bf(W2[(e*256 + k0 + j)*128 + n]);
        *(short8v*)&W2F[t*8] = *(short8v*)v;
    }
}

// ---------------------------------------------------------------------------
// Persistent cooperative kernel: 133 WGs x 256 threads. WG g owns chunk g of
// every level. Cross-XCD coherence via agent-scope (sc1, L2-bypass) accesses
// for inter-level data only; weights stay L2-cached. Level barrier is one
// relaxed atomicAdd per WG + release-flag poll. NO wbl2/inv fences.
// ---------------------------------------------------------------------------
__global__ __launch_bounds__(256, 1) void persist_mfma(
    const unsigned short* __restrict__ W1F, const unsigned short* __restrict__ W2F,
    const float* __restrict__ b1, const float* __restrict__ b2,
    const float* __restrict__ slots, const int* __restrict__ par,
    const int* __restrict__ types, const unsigned short* __restrict__ order,
    float* __restrict__ buf, int* __restrict__ barmem)
{
    __shared__ int4 descs[LL][NBK];            // 16 KB: {node, p0, p1(~slot if out), etype}
    __shared__ int ech[LL];                    // per-level chunk encoder type (-1 = all pad)
    __shared__ unsigned short axF[8*64*8];     // A-frags of x, 8 KB
    __shared__ unsigned short hxF[8*64*8];     // A-frags of h, 8 KB

    int tid = threadIdx.x;
    int wg  = blockIdx.x;

    // ---- prologue: resolve all 64 levels' descriptors for this WG ----
    for (int i = tid; i < LL*NBK; i += 256) {
        int l = i >> 4, s = i & 15;
        unsigned short o = order[l*PAD16 + wg*NBK + s];
        int4 d;
        if (o == 0xFFFFu) {
            d = make_int4(-1, 0, 0, -1);
        } else {
            int gi = l*MM + (int)o;
            int t = types[gi];
            int e = (t >= TT) ? TT : t;
            int p0 = par[2*gi];
            int p1 = (t >= TT) ? ~(t - TT) : par[2*gi + 1];
            d = make_int4((int)o, p0, p1, e);
        }
        descs[l][s] = d;
    }
    __syncthreads();
    for (int i = tid; i < LL; i += 256) ech[i] = descs[i][0].w;
    __syncthreads();

    int w  = tid >> 6;    // wave 0..3
    int lq = tid & 63;    // lane
    int* cntp = barmem;        // arrival counter (line 0)
    int* flgp = barmem + 32;   // release flag   (line 1)

    for (int l = 0; l < LL; l++) {
        // ---- level barrier (skip l=0: prep kernels ordered by stream) ----
        if (l > 0) {
            __syncthreads();   // each wave drains vmcnt(0) before s_barrier ->
                               // all this WG's sc1 stores are at the coherence point
            if (tid == 0) {
                asm volatile("s_waitcnt vmcnt(0)" ::: "memory");
                int old = __hip_atomic_fetch_add(cntp, 1, __ATOMIC_RELAXED, __HIP_MEMORY_SCOPE_AGENT);
                if (old == l*CH - 1) {
                    __hip_atomic_store(flgp, l, __ATOMIC_RELAXED, __HIP_MEMORY_SCOPE_AGENT);
                } else {
                    while (__hip_atomic_load(flgp, __ATOMIC_RELAXED, __HIP_MEMORY_SCOPE_AGENT) < l)
                        __builtin_amdgcn_s_sleep(4);
                }
            }
            __syncthreads();
        }

        int e = ech[l];
        if (e < 0) continue;   // fully-padded chunk (uniform across WG)

        // ---- gather x = [buf[p0] | is_out ? slot : buf[p1]] into A-frag LDS ----
        // coherent (L2-bypass) loads: sources were written by other XCDs
        {
            int m = tid >> 4, seg = tid & 15;      // node m, 16-float segment
            int4 d = descs[l][m];
            float vals[16];
            if (d.x >= 0) {
                const float* src;
                if (seg < 8) {
                    src = buf + (size_t)d.y*DD + seg*16;
                } else if (d.z < 0) {
                    src = slots + (size_t)(~d.z)*DD + (seg - 8)*16;
                } else {
                    src = buf + (size_t)d.z*DD + (seg - 8)*16;
                }
                unsigned long long* s8 = (unsigned long long*)src;
                unsigned long long u[8];
                #pragma unroll
                for (int q = 0; q < 8; q++)
                    u[q] = __hip_atomic_load(&s8[q], __ATOMIC_RELAXED, __HIP_MEMORY_SCOPE_AGENT);
                #pragma unroll
                for (int q = 0; q < 8; q++) {
                    vals[2*q+0] = __uint_as_float((unsigned)(u[q] & 0xFFFFFFFFull));
                    vals[2*q+1] = __uint_as_float((unsigned)(u[q] >> 32));
                }
            } else {
                #pragma unroll
                for (int q = 0; q < 16; q++) vals[q] = 0.f;
            }
            #pragma unroll
            for (int h = 0; h < 2; h++) {
                int k = seg*16 + h*8;
                int kk = k >> 5;
                int lane = m + 16*((k >> 3) & 3);
                unsigned short tmp[8];
                #pragma unroll
                for (int j = 0; j < 8; j++) tmp[j] = f2bf(vals[h*8 + j]);
                *(short8v*)&axF[(kk*64 + lane)*8] = *(short8v*)tmp;
            }
        }
        __syncthreads();

        // ---- layer 1: H = GELU(X @ W1[e] + b1[e]) ----
        f32x4 acc[4];
        #pragma unroll
        for (int c = 0; c < 4; c++) {
            float bv = b1[e*256 + w*64 + c*16 + (lq & 15)];
            acc[c] = (f32x4){bv, bv, bv, bv};
        }
        {
            const short8v* Ab = (const short8v*)axF;
            #pragma unroll
            for (int kk = 0; kk < 8; kk++) {
                short8v a = Ab[kk*64 + lq];
                #pragma unroll
                for (int c = 0; c < 4; c++) {
                    int nt = w*4 + c;
                    short8v bfr = *(const short8v*)&W1F[(((e*16 + nt)*8 + kk)*64 + lq)*8];
                    acc[c] = __builtin_amdgcn_mfma_f32_16x16x32_bf16(a, bfr, acc[c], 0, 0, 0);
                }
            }
        }
        #pragma unroll
        for (int c = 0; c < 4; c++) {
            int nh = w*64 + c*16 + (lq & 15);    // hidden index = layer2's k
            int kk2 = nh >> 5;
            int jj  = nh & 7;
            int lhi = 16*((nh >> 3) & 3);
            #pragma unroll
            for (int r = 0; r < 4; r++) {
                int m = (lq >> 4)*4 + r;
                float h = acc[c][r];
                float gg = 0.5f*h*(1.0f + erff(h*0.70710678118654752f));
                hxF[(kk2*64 + (m + lhi))*8 + jj] = f2bf(gg);
            }
        }
        __syncthreads();

        // ---- layer 2: OUT = H @ W2[e] + b2[e] ----
        f32x4 acc2[2];
        #pragma unroll
        for (int c = 0; c < 2; c++) {
            float bv = b2[e*128 + w*32 + c*16 + (lq & 15)];
            acc2[c] = (f32x4){bv, bv, bv, bv};
        }
        {
            const short8v* Hb = (const short8v*)hxF;
            #pragma unroll
            for (int kk = 0; kk < 8; kk++) {
                short8v a = Hb[kk*64 + lq];
                #pragma unroll
                for (int c = 0; c < 2; c++) {
                    int nt = w*2 + c;
                    short8v bfr = *(const short8v*)&W2F[(((e*8 + nt)*8 + kk)*64 + lq)*8];
                    acc2[c] = __builtin_amdgcn_mfma_f32_16x16x32_bf16(a, bfr, acc2[c], 0, 0, 0);
                }
            }
        }
        // write-through (L2-bypass) stores -> visible at coherence point
        int baserow = RR + l*MM;
        #pragma unroll
        for (int r = 0; r < 4; r++) {
            int m = (lq >> 4)*4 + r;
            int node = descs[l][m].x;
            if (node >= 0) {
                #pragma unroll
                for (int c = 0; c < 2; c++) {
                    int n = w*32 + c*16 + (lq & 15);
                    __hip_atomic_store(&buf[(size_t)(baserow + node)*DD + n], acc2[c][r],
                                       __ATOMIC_RELAXED, __HIP_MEMORY_SCOPE_AGENT);
                }
            }
        }
        // barrier at top of next iteration publishes these stores
    }
}

extern "C" void kernel_launch(void* const* d_in, const int* in_sizes, int n_in,
                              void* d_out, int out_size, void* d_ws, size_t ws_size,
                              hipStream_t stream) {
    const float* root  = (const float*)d_in[0];   // (1024, 128)
    const float* W1    = (const float*)d_in[1];   // (5, 256, 256)
    const float* b1    = (const float*)d_in[2];   // (5, 256)
    const float* W2    = (const float*)d_in[3];   // (5, 256, 128)
    const float* b2    = (const float*)d_in[4];   // (5, 128)
    const float* slots = (const float*)d_in[5];   // (256, 128)
    const int*   par   = (const int*)d_in[6];     // (131072, 2)
    const int*   typ   = (const int*)d_in[7];     // (131072,)
    float* out = (float*)d_out;                   // (132096, 128)

    unsigned short* W1F   = (unsigned short*)d_ws;            // 327680 shorts
    unsigned short* W2F   = W1F + 5*16*8*64*8;                // 163840 shorts
    unsigned short* order = W2F + 5*8*8*64*8;                 // 64*2128 shorts
    int* barmem = (int*)(order + LL*PAD16);                   // 64 ints (2 lines)

    // roots -> buf[0:R]
    hipMemcpyAsync(out, root, (size_t)RR * DD * sizeof(float),
                   hipMemcpyDeviceToDevice, stream);

    // per-call prep
    build_order16<<<LL, 256, 0, stream>>>(typ, order);
    convert_weights<<<(5*16*8*64 + 5*8*8*64 + 255)/256, 256, 0, stream>>>(W1, W2, W1F, W2F);
    hipMemsetAsync(barmem, 0, 64*sizeof(int), stream);

    // persistent cooperative sweep over all 64 levels
    void* args[] = { (void*)&W1F, (void*)&W2F, (void*)&b1, (void*)&b2,
                     (void*)&slots, (void*)&par, (void*)&typ, (void*)&order,
                     (void*)&out, (void*)&barmem };
    hipLaunchCooperativeKernel((const void*)persist_mfma, dim3(CH), dim3(256),
                               args, 0, stream);
}